// Round 16
// baseline (321.376 us; speedup 1.0000x reference)
//
#include <hip/hip_runtime.h>
#include <hip/hip_bf16.h>

#define DEV __device__ __forceinline__

static constexpr int Bsz   = 16;
static constexpr int Aseq  = 512;
static constexpr int Datom = 256;
static constexpr int NL    = 4;
static constexpr int DI    = 512;   // d_inner
static constexpr int NH    = 8;     // heads
static constexpr int DPROJ = 1160;
static constexpr int PSTR  = 1280;  // padded proj row stride
static constexpr int Mrows = Bsz * Aseq;  // 8192
static constexpr int NC    = 8;     // chunks
static constexpr int CB    = 64;    // chunk size

typedef __attribute__((ext_vector_type(8))) short short8;
typedef __attribute__((ext_vector_type(4))) float f32x4;
typedef unsigned int u32;
typedef unsigned short u16;

DEV u16 f2bf(float x) {
  __hip_bfloat16 h = __float2bfloat16(x);   // RNE, compiler pairs to cvt_pk
  u16 r; __builtin_memcpy(&r, &h, 2); return r;
}
DEV float bf2f(u16 b) {
  union { unsigned u; float f; } v; v.u = ((unsigned)b) << 16;
  return v.f;
}
DEV float fsilu(float x) {
  return x * __builtin_amdgcn_rcpf(1.f + __expf(-x));
}

DEV void gload16(const u16* g, u16* l) {
  __builtin_amdgcn_global_load_lds(
      (const __attribute__((address_space(1))) u32*)g,
      (__attribute__((address_space(3))) u32*)l, 16, 0, 0);
}

template<int NW>
DEV float block_sum(float v, float* sbuf) {
  int lane = threadIdx.x & 63, wid = threadIdx.x >> 6;
#pragma unroll
  for (int o = 32; o > 0; o >>= 1) v += __shfl_down(v, o);
  if (lane == 0) sbuf[wid] = v;
  __syncthreads();
  if (wid == 0) {
    float t = (lane < NW) ? sbuf[lane] : 0.f;
#pragma unroll
    for (int o = 4; o > 0; o >>= 1) t += __shfl_down(t, o);
    if (lane == 0) sbuf[0] = t;
  }
  __syncthreads();
  float r = sbuf[0];
  __syncthreads();
  return r;
}

// ===== PROLOGUE: weights transpose | mask build | rmsnorm+copy ==========
// flat grid: [0,1440) weights tiles, [1440,1472) mask, [1472,9664) rmsnorm.
__global__ __launch_bounds__(256)
void prologue(const void* mask_raw, float* maskf,
              const float* w_in, const float* w_out, const float* w1,
              u16* winT, u16* woutT, u16* w1T,
              const float* atok, const float* pre_w, float* tok, u16* xin) {
  __shared__ float T[64][65];
  __shared__ float sred[16];
  __shared__ int cnz, c3f;
  int bid = blockIdx.x, tid = threadIdx.x;

  if (bid < 1440) {
    int x = bid & 7, y = (bid >> 3) % 20, z = bid / 160;
    const float* src; u16* dst; int K, N, Npad;
    if (z < 4) {
      src = w_in + (size_t)z * Datom * DPROJ; dst = winT + (size_t)z * PSTR * Datom;
      K = Datom; N = DPROJ; Npad = PSTR;
    } else if (z < 8) {
      int l = z - 4;
      src = w_out + (size_t)l * DI * Datom; dst = woutT + (size_t)l * Datom * DI;
      K = DI; N = Datom; Npad = Datom;
    } else {
      src = w1; dst = w1T; K = Datom; N = 128; Npad = 128;
    }
    int k0 = x * 64, n0 = y * 64;
    if (k0 >= K || n0 >= Npad) return;
#pragma unroll
    for (int i = 0; i < 16; i++) {
      int lin = tid + i * 256;
      int kk = lin >> 6, nn = lin & 63;
      int n = n0 + nn;
      T[kk][nn] = (n < N) ? src[(size_t)(k0 + kk) * N + n] : 0.f;
    }
    __syncthreads();
#pragma unroll
    for (int i = 0; i < 16; i++) {
      int lin = tid + i * 256;
      int nn = lin >> 6, kk = lin & 63;
      dst[(size_t)(n0 + nn) * K + k0 + kk] = f2bf(T[kk][nn]);
    }
  } else if (bid < 1472) {
    if (tid == 0) { cnz = 0; c3f = 0; }
    __syncthreads();
    const unsigned char* mb = (const unsigned char*)mask_raw;
    int nz = 0, f3 = 0;
    for (int i = tid; i < 8192; i += 256) {
      unsigned char v = mb[i];
      nz += (v != 0);
      f3 += (v == 0x3f);
    }
    atomicAdd(&cnz, nz);
    atomicAdd(&c3f, f3);
    __syncthreads();
    int fl = (c3f > 500) ? 2 : ((cnz > 4500) ? 0 : 1);
    int i = (bid - 1440) * 256 + tid;
    float v;
    if (fl == 0)      v = ((const unsigned char*)mask_raw)[i] ? 1.f : 0.f;
    else if (fl == 1) v = ((const int*)mask_raw)[i] ? 1.f : 0.f;
    else              v = (((const float*)mask_raw)[i] != 0.f) ? 1.f : 0.f;
    maskf[i] = v;
  } else {
    int row = bid - 1472, c = tid;
    float v = atok[(size_t)row * Datom + c];
    tok[(size_t)row * Datom + c] = v;
    float tot = block_sum<4>(v * v, sred);
    float scale = rsqrtf(tot / (float)Datom + 1e-6f);
    xin[(size_t)row * Datom + c] = f2bf(v * scale * pre_w[c]);
  }
}

// ---------------- in-proj 128x128 bf16 MFMA GEMM (cols 0..1152) ---------
__global__ __launch_bounds__(256)
void gemm_in(const u16* Abf, const u16* BTbf, u16* outp, int Ndim, int Kdim) {
  __shared__ __align__(16) u16 As[128 * 32];
  __shared__ __align__(16) u16 Bs[128 * 32];
  int tid = threadIdx.x, w = tid >> 6, lane = tid & 63;
  int wm = w >> 1, wn = w & 1;
  int r0 = blockIdx.x * 128, c0 = blockIdx.y * 128;
  int lq = lane >> 4, lr = lane & 15;
  const u16* Ag = Abf + (size_t)r0 * Kdim;
  const u16* Bg = BTbf + (size_t)c0 * Kdim;
  int srow[2], scol = (lane & 3) * 8;
  u16* ldst[2][2];
#pragma unroll
  for (int rr = 0; rr < 2; rr++) {
    int chunk = rr * 4 + w;
    srow[rr] = chunk * 16 + (lane >> 2);
    ldst[rr][0] = As + chunk * 512;
    ldst[rr][1] = Bs + chunk * 512;
  }
  f32x4 acc[4][4];
#pragma unroll
  for (int i = 0; i < 4; i++)
#pragma unroll
    for (int j = 0; j < 4; j++)
#pragma unroll
      for (int r = 0; r < 4; r++) acc[i][j][r] = 0.f;

  for (int k0 = 0; k0 < Kdim; k0 += 32) {
    __syncthreads();
#pragma unroll
    for (int rr = 0; rr < 2; rr++) {
      gload16(Ag + (size_t)srow[rr] * Kdim + k0 + scol, ldst[rr][0]);
      gload16(Bg + (size_t)srow[rr] * Kdim + k0 + scol, ldst[rr][1]);
    }
    __syncthreads();
    short8 af[4], bfr[4];
#pragma unroll
    for (int i = 0; i < 4; i++)
      af[i] = *(const short8*)(As + (wm * 64 + i * 16 + lr) * 32 + lq * 8);
#pragma unroll
    for (int j = 0; j < 4; j++)
      bfr[j] = *(const short8*)(Bs + (wn * 64 + j * 16 + lr) * 32 + lq * 8);
#pragma unroll
    for (int i = 0; i < 4; i++)
#pragma unroll
      for (int j = 0; j < 4; j++)
        acc[i][j] = __builtin_amdgcn_mfma_f32_16x16x32_bf16(af[i], bfr[j], acc[i][j], 0, 0, 0);
  }
#pragma unroll
  for (int i = 0; i < 4; i++)
#pragma unroll
    for (int j = 0; j < 4; j++)
#pragma unroll
      for (int r = 0; r < 4; r++) {
        int row = r0 + wm * 64 + i * 16 + lq * 4 + r;
        int col = c0 + wn * 64 + j * 16 + lr;
        outp[(size_t)row * Ndim + col] = f2bf(acc[i][j][r]);
      }
}

// ---- gate (y*silu(z), rms) + out-proj GEMM + residual + (rms | LN+head) --
template<int MODE>
__global__ __launch_bounds__(256)
void gemm_gate_out(const u16* ysumb, const u16* projb, const float* rw,
                   const u16* BTbf, const float* tok_in,
                   const float* aux1, const float* aux2,
                   float* tok_out, u16* dst16,
                   const u16* w1Tp, const float* b1p, const float* w2p,
                   const float* b2p, const float* maskfp, float* outf) {
  __shared__ __align__(16) u16 As[32 * 512];   // gated+normalized A (swizzled)
  __shared__ __align__(16) u16 Bs[256 * 32];
  __shared__ float part1[32][4];
  __shared__ float part2[32][4];
  int tid = threadIdx.x, w = tid >> 6, lane = tid & 63;
  int lq = lane >> 4, lr = lane & 15;
  int r0 = blockIdx.x * 32;

  // Phase A: gate + rms, values kept in registers, single LDS write.
  {
    int arow = tid >> 3, sub = tid & 7;
    size_t yb = (size_t)(r0 + arow) * DI;
    size_t pb = (size_t)(r0 + arow) * PSTR;
    short8 g8s[8];
    float sumsq = 0.f;
#pragma unroll
    for (int o = 0; o < 8; o++) {
      int col = sub * 64 + o * 8;
      short8 yv = *(const short8*)(ysumb + yb + col);
      short8 zv = *(const short8*)(projb + pb + col);
#pragma unroll
      for (int e = 0; e < 8; e++) {
        float y = bf2f((u16)yv[e]);
        float z = bf2f((u16)zv[e]);
        float g = y * z * __builtin_amdgcn_rcpf(1.f + __expf(-z));
        sumsq += g * g;
        g8s[o][e] = (short)f2bf(g);
      }
    }
#pragma unroll
    for (int m = 1; m < 8; m <<= 1) sumsq += __shfl_xor(sumsq, m);
    float scl = rsqrtf(sumsq / (float)DI + 1e-6f);
#pragma unroll
    for (int o = 0; o < 8; o++) {
      int col = sub * 64 + o * 8;
      int oct = (sub * 8 + o) ^ (arow & 7);
      short8 g8 = g8s[o];
      f32x4 w0 = *(const f32x4*)(rw + col);
      f32x4 w1 = *(const f32x4*)(rw + col + 4);
#pragma unroll
      for (int e = 0; e < 4; e++) {
        g8[e]     = (short)f2bf(bf2f((u16)g8[e]) * scl * w0[e]);
        g8[4 + e] = (short)f2bf(bf2f((u16)g8[4 + e]) * scl * w1[e]);
      }
      *(short8*)(As + arow * 512 + oct * 8) = g8;
    }
  }

  // Phase B: K-loop, A from LDS (persistent), B staged per iter.
  f32x4 acc[2][4];
#pragma unroll
  for (int i = 0; i < 2; i++)
#pragma unroll
    for (int j = 0; j < 4; j++)
#pragma unroll
      for (int r = 0; r < 4; r++) acc[i][j][r] = 0.f;

  for (int k0 = 0; k0 < 512; k0 += 32) {
    __syncthreads();
#pragma unroll
    for (int rr = 0; rr < 4; rr++) {
      int l = tid + rr * 256;
      int row = l >> 2, cc = l & 3;
      gload16(BTbf + (size_t)row * 512 + k0 + cc * 8, Bs + l * 8);
    }
    __syncthreads();
    int kq = k0 >> 3;
    short8 af[2], bfr[4];
#pragma unroll
    for (int i = 0; i < 2; i++) {
      int row = i * 16 + lr;
      af[i] = *(const short8*)(As + row * 512 + (((kq + lq) ^ (row & 7)) * 8));
    }
#pragma unroll
    for (int j = 0; j < 4; j++)
      bfr[j] = *(const short8*)(Bs + (w * 64 + j * 16 + lr) * 32 + lq * 8);
#pragma unroll
    for (int i = 0; i < 2; i++)
#pragma unroll
      for (int j = 0; j < 4; j++)
        acc[i][j] = __builtin_amdgcn_mfma_f32_16x16x32_bf16(af[i], bfr[j], acc[i][j], 0, 0, 0);
  }

  // Epilogue: residual + rowwise reduce + (rms | LN)
#pragma unroll
  for (int i = 0; i < 2; i++)
#pragma unroll
    for (int r = 0; r < 4; r++) {
      int lrow = i * 16 + lq * 4 + r;
      int row = r0 + lrow;
      float s1 = 0.f, s2 = 0.f;
#pragma unroll
      for (int j = 0; j < 4; j++) {
        int col = w * 64 + j * 16 + lr;
        float v = acc[i][j][r] + tok_in[(size_t)row * Datom + col];
        acc[i][j][r] = v;
        tok_out[(size_t)row * Datom + col] = v;
        s1 += v;
        s2 += v * v;
      }
#pragma unroll
      for (int m = 1; m < 16; m <<= 1) {
        s1 += __shfl_xor(s1, m);
        s2 += __shfl_xor(s2, m);
      }
      if (lr == 0) {
        part1[lrow][w] = s1;
        part2[lrow][w] = s2;
      }
    }
  __syncthreads();
#pragma unroll
  for (int i = 0; i < 2; i++)
#pragma unroll
    for (int r = 0; r < 4; r++) {
      int lrow = i * 16 + lq * 4 + r;
      int row = r0 + lrow;
      float t2 = part2[lrow][0] + part2[lrow][1] + part2[lrow][2] + part2[lrow][3];
      if constexpr (MODE == 1) {
        float scale = rsqrtf(t2 / (float)Datom + 1e-6f);
#pragma unroll
        for (int j = 0; j < 4; j++) {
          int col = w * 64 + j * 16 + lr;
          dst16[(size_t)row * Datom + col] = f2bf(acc[i][j][r] * scale * aux1[col]);
        }
      } else {
        float t1 = part1[lrow][0] + part1[lrow][1] + part1[lrow][2] + part1[lrow][3];
        float mu = t1 / (float)Datom;
        float var = t2 / (float)Datom - mu * mu;
        float rs = rsqrtf(var + 1e-5f);
#pragma unroll
        for (int j = 0; j < 4; j++) {
          int col = w * 64 + j * 16 + lr;
          float lnv = (acc[i][j][r] - mu) * rs * aux1[col] + aux2[col];
          int chunk = col >> 5;
          int cc = col & 31;
          As[chunk * 1024 + lrow * 32 + cc] = f2bf(lnv);
        }
      }
    }

  if constexpr (MODE == 2) {
    // ---- head: h1 = lnb32x256 @ w1T; gelu; dot w2 + b2; *mask -> outf ----
    __shared__ float hpart[32][2][3];
    __shared__ float sw2[387];
    for (int g = tid; g < 387; g += 256)
      sw2[g] = (g < 384) ? w2p[g] : b2p[g - 384];
    int wm2 = w >> 1, wn2 = w & 1;
    f32x4 hacc[4];
#pragma unroll
    for (int j = 0; j < 4; j++)
#pragma unroll
      for (int r = 0; r < 4; r++) hacc[j][r] = 0.f;

    for (int k0 = 0; k0 < 256; k0 += 32) {
      __syncthreads();
      {
        int l = tid, row = l >> 2, cc2 = l & 3;
        gload16(w1Tp + (size_t)row * 256 + k0 + cc2 * 8, Bs + l * 8);
        l = tid + 256; row = l >> 2; cc2 = l & 3;
        gload16(w1Tp + (size_t)row * 256 + k0 + cc2 * 8, Bs + l * 8);
      }
      __syncthreads();
      short8 af = *(const short8*)(As + (k0 >> 5) * 1024 + (wm2 * 16 + lr) * 32 + lq * 8);
#pragma unroll
      for (int j = 0; j < 4; j++) {
        short8 bfr = *(const short8*)(Bs + (wn2 * 64 + j * 16 + lr) * 32 + lq * 8);
        hacc[j] = __builtin_amdgcn_mfma_f32_16x16x32_bf16(af, bfr, hacc[j], 0, 0, 0);
      }
    }
#pragma unroll
    for (int r = 0; r < 4; r++) {
      int lrow2 = wm2 * 16 + lq * 4 + r;
      float p0 = 0.f, p1 = 0.f, p2 = 0.f;
#pragma unroll
      for (int j = 0; j < 4; j++) {
        int col = wn2 * 64 + j * 16 + lr;
        float v = hacc[j][r] + b1p[col];
        float ge = 0.5f * v * (1.f + erff(v * 0.70710678118654752f));
        p0 += ge * sw2[col * 3 + 0];
        p1 += ge * sw2[col * 3 + 1];
        p2 += ge * sw2[col * 3 + 2];
      }
#pragma unroll
      for (int m = 1; m < 16; m <<= 1) {
        p0 += __shfl_xor(p0, m);
        p1 += __shfl_xor(p1, m);
        p2 += __shfl_xor(p2, m);
      }
      if (lr == 0) {
        hpart[lrow2][wn2][0] = p0;
        hpart[lrow2][wn2][1] = p1;
        hpart[lrow2][wn2][2] = p2;
      }
    }
    __syncthreads();
    if (tid < 32) {
      int row = r0 + tid;
      float mk = maskfp[row];
#pragma unroll
      for (int k = 0; k < 3; k++)
        outf[(size_t)row * 3 + k] =
            (hpart[tid][0][k] + hpart[tid][1][k] + sw2[384 + k]) * mk;
    }
  }
}

// ---------------- chunked SSD scan helpers -------------------------------
DEV int swz(int r, int c)  { return (r << 6) | (c ^ ((r & 7) << 3)); }  // bf16 [64][64]

DEV short8 ldfrag(const u16* M, int row, int k0) {
  return *(const short8*)(M + swz(row, k0));
}
DEV short8 scale8(short8 a, float s) {
  short8 r;
#pragma unroll
  for (int i = 0; i < 8; i++) r[i] = (short)f2bf(bf2f((u16)a[i]) * s);
  return r;
}
DEV short8 scale8v(short8 a, const float* s) {
  short8 r;
#pragma unroll
  for (int i = 0; i < 8; i++) r[i] = (short)f2bf(bf2f((u16)a[i]) * s[i]);
  return r;
}

// Pass 1: dt-GEMV + conv + local scan fused. 4 barriers.
__global__ __launch_bounds__(256, 4)
void scan_fused(const u16* projb, const u16* xin, const u16* winT_l,
                const float* cw, const float* A_log, const float* dt_bias,
                const float* Dpv, const float* maskf,
                u16* ysumb, u16* Hcb, float* carrySc, float* eTot) {
  int b = blockIdx.x, h = blockIdx.y, chunk = blockIdx.z;
  int tid = threadIdx.x, w = tid >> 6, lane = tid & 63;
  int lq = lane >> 4, lr = lane & 15;
  __shared__ __align__(16) u16 Cmat[4096];  // C [t][n]; then S_sum
  __shared__ __align__(16) u16 Bmat[4096];  // B [s][n]
  __shared__ __align__(16) u16 XTm[4096];   // [p][s] swizzled
  __shared__ __align__(16) union { u16 BTm[4096]; u16 XCs[4416]; } U;
  __shared__ float cws[4][64];
  __shared__ float dtp[4][64];
  __shared__ float Pp[64], Qq[64], scf[64], scb[64], dts[64], ms[64], dpo[64];
  int base_t = chunk * CB;
  int sdi2 = b * NH + h;
  size_t rowbase = (size_t)b * Aseq + base_t;

  // [A0] dt GEMV: dt_raw[row] = xin[rowbase+row][:] . winT[1152+h][:]
  {
    int row = tid & 63, kq = tid >> 6;
    const u16* xr = xin + (rowbase + row) * Datom + kq * 64;
    const u16* wr = winT_l + (size_t)(1152 + h) * Datom + kq * 64;
    float acc = 0.f;
#pragma unroll
    for (int k = 0; k < 64; k += 8) {
      short8 xv = *(const short8*)(xr + k);
      short8 wv = *(const short8*)(wr + k);
#pragma unroll
      for (int e = 0; e < 8; e++)
        acc += bf2f((u16)xv[e]) * bf2f((u16)wv[e]);
    }
    dtp[kq][row] = acc;
  }
  __syncthreads();  // (0)

  // [A] per-t scalars + decay prefix (wave 0); all waves then stage
  if (w == 0) {
    float mk = maskf[rowbase + lane];
    float dtr = dtp[0][lane] + dtp[1][lane] + dtp[2][lane] + dtp[3][lane]
                + dt_bias[h];
    float dtv = (dtr > 20.f) ? dtr : log1pf(expf(dtr));
    dtv *= mk;
    float lv = -expf(A_log[h]) * dtv;
    dts[lane] = dtv;
    ms[lane] = mk;
    dpo[lane] = Dpv[h] / fmaxf(dtv, 1e-30f);
    float v = lv;
#pragma unroll
    for (int o = 1; o < 64; o <<= 1) {
      float u = __shfl_up(v, o);
      if (lane >= o) v += u;
    }
    float Ltot = __shfl(v, 63);
    Pp[lane] = v;
    Qq[lane] = v - lv;
    scf[lane] = __expf(Ltot - v);
    scb[lane] = __expf(v - lv);
    size_t cs = ((size_t)sdi2 * NC + chunk) * 128;
    carrySc[cs + lane] = __expf(v);
    carrySc[cs + 64 + lane] = __expf(Ltot - (v - lv));
    if (lane == 0) eTot[sdi2 * NC + chunk] = __expf(Ltot);
  }
  // [B] stage B,C + conv window XCs (stride-69, conflict-free)
  for (int g = tid; g < 1024; g += 256) {
    int t = g >> 4, cc0 = (g & 15) * 8;
    short8 v = *(const short8*)(projb + (rowbase + t) * PSTR + 1024 + cc0);
    if (cc0 < 64) *(short8*)(Bmat + swz(t, cc0)) = v;
    else          *(short8*)(Cmat + swz(t, cc0 - 64)) = v;
  }
  for (int g = tid; g < 536; g += 256) {
    int ti = g >> 3, p0 = (g & 7) * 8;
    if (ti < 67) {
      int tg = base_t - 3 + ti;
      short8 v;
      if (tg >= 0) {
        v = *(const short8*)(projb + ((size_t)b * Aseq + tg) * PSTR + DI + h * 64 + p0);
      } else {
#pragma unroll
        for (int e = 0; e < 8; e++) v[e] = 0;
      }
#pragma unroll
      for (int e = 0; e < 8; e++) U.XCs[(p0 + e) * 69 + ti] = (u16)v[e];
    }
  }
  cws[tid >> 6][tid & 63] = cw[(tid >> 6) * DI + h * 64 + (tid & 63)];
  __syncthreads();  // (1)

  // [P2] conv -> XTm  AND  G = C @ B^T (both consume only staged data)
  f32x4 accG[4];
#pragma unroll
  for (int j = 0; j < 4; j++)
#pragma unroll
    for (int r = 0; r < 4; r++) accG[j][r] = 0.f;
#pragma unroll
  for (int kk = 0; kk < 2; kk++) {
    int k0 = kk * 32 + lq * 8;
    short8 afr = ldfrag(Cmat, w * 16 + lr, k0);
#pragma unroll
    for (int j = 0; j < 4; j++)
      accG[j] = __builtin_amdgcn_mfma_f32_16x16x32_bf16(
          afr, ldfrag(Bmat, j * 16 + lr, k0), accG[j], 0, 0, 0);
  }
  for (int g = tid; g < 4096; g += 256) {
    int p = g >> 6, t = g & 63;
    float acc = 0.f;
#pragma unroll
    for (int k = 0; k < 4; k++)
      acc += cws[k][p] * bf2f(U.XCs[p * 69 + t + k]);
    float xcv = fsilu(acc) * ms[t];
    XTm[swz(p, t)] = f2bf(xcv * dts[t]);
  }
  __syncthreads();  // (2) XCs/Cmat reads done

  int trow[4];
#pragma unroll
  for (int r = 0; r < 4; r++) trow[r] = w * 16 + lq * 4 + r;

  // [P3] S_sum -> Cmat (diag: 2*G + D/dt)  AND  BTm build (over XCs)
#pragma unroll
  for (int j = 0; j < 4; j++) {
    int s = j * 16 + lr;
    float Ls = Pp[s], Qs = Qq[s];
#pragma unroll
    for (int r = 0; r < 4; r++) {
      int t = trow[r];
      float g = 0.f;
      if (s <= t) g += accG[j][r] * __expf(Pp[t] - Ls);
      if (s >= t) g += accG[j][r] * __expf(Qs - Qq[t]);
      if (s == t) g += dpo[s];
      Cmat[swz(t, s)] = f2bf(g);
    }
  }
  for (int g = tid; g < 512; g += 256) {
    int t = g & 63, n0 = (g >> 6) * 8;
    short8 v = *(const short8*)(Bmat + swz(t, n0));
#pragma unroll
    for (int e = 0; e < 8; e++) U.BTm[swz(n0 + e, t)] = (u16)v[e];
  }
  __syncthreads();  // (3)

  // [P4] combined Y + H_fwd + H_bwd
  f32x4 accY[4], accHf[4], accHb[4];
#pragma unroll
  for (int j = 0; j < 4; j++)
#pragma unroll
    for (int r = 0; r < 4; r++) { accY[j][r] = 0.f; accHf[j][r] = 0.f; accHb[j][r] = 0.f; }
#pragma unroll
  for (int kk = 0; kk < 2; kk++) {
    int k0 = kk * 32 + lq * 8;
    short8 aS  = ldfrag(Cmat, w * 16 + lr, k0);
    short8 aX  = ldfrag(XTm,  w * 16 + lr, k0);
    short8 aXf = scale8v(aX, &scf[k0]);
    short8 aXb = scale8v(aX, &scb[k0]);
#pragma unroll
    for (int j = 0; j < 4; j++)
      accY[j] = __builtin_amdgcn_mfma_f32_16x16x32_bf16(
          aS, ldfrag(XTm, j * 16 + lr, k0), accY[j], 0, 0, 0);
#pragma unroll
    for (int j = 0; j < 4; j++) {
      short8 bB = ldfrag(U.BTm, j * 16 + lr, k0);
      accHf[j] = __builtin_amdgcn_mfma_f32_16x16x32_bf16(aXf, bB, accHf[j], 0, 0, 0);
      accHb[j] = __builtin_amdgcn_mfma_f32_16x16x32_bf16(aXb, bB, accHb[j], 0, 0, 0);
    }
  }
  size_t hbf = ((size_t)(sdi2 * 2 + 0) * NC + chunk) * 4096;
  size_t hbb = ((size_t)(sdi2 * 2 + 1) * NC + chunk) * 4096;
#pragma unroll
  for (int j = 0; j < 4; j++) {
    int rn = j * 16 + lr;
#pragma unroll
    for (int r = 0; r < 4; r++) {
      int p = w * 16 + lq * 4 + r;
      Hcb[hbf + p * 64 + rn] = f2bf(accHf[j][r]);
      Hcb[hbb + p * 64 + rn] = f2bf(accHb[j][r]);
    }
  }
#pragma unroll
  for (int j = 0; j < 4; j++) {
    int p = j * 16 + lr;
#pragma unroll
    for (int r = 0; r < 4; r++)
      ysumb[(rowbase + trow[r]) * DI + h * 64 + p] = f2bf(accY[j][r]);
  }
}

// Pass 2: ysumb += carries IN PLACE; H_init = weighted sums of chunk states.
__global__ __launch_bounds__(256, 4)
void carry_add(const u16* projb, const u16* Hcb, const float* carrySc,
               const float* eTot, u16* ysumb) {
  int b = blockIdx.x, h = blockIdx.y, chunk = blockIdx.z;
  int tid = threadIdx.x, w = tid >> 6, lane = tid & 63;
  int lq = lane >> 4, lr = lane & 15;
  __shared__ __align__(16) u16 Cmat[4096];
  __shared__ __align__(16) u16 HTf[4096], HTb[4096];
  __shared__ float scf[64], scb[64];
  int base_t = chunk * CB;
  int sdi2 = b * NH + h;
  size_t rowbase = (size_t)b * Aseq + base_t;

  if (tid < 128) {
    size_t cs = ((size_t)sdi2 * NC + chunk) * 128;
    float v = carrySc[cs + tid];
    if (tid < 64) scf[tid] = v; else scb[tid - 64] = v;
  }
  for (int g = tid; g < 512; g += 256) {
    int t = g >> 3, n0 = (g & 7) * 8;
    *(short8*)(Cmat + swz(t, n0)) =
        *(const short8*)(projb + (rowbase + t) * PSTR + 1088 + n0);
  }
  {
    float wfd[7], wbd[7];
    float Wf = 1.f, Wb = 1.f;
#pragma unroll
    for (int d = 1; d <= 7; d++) {
      int jf = chunk - d, jb = chunk + d;
      wfd[d - 1] = (jf >= 0) ? Wf : 0.f;
      if (jf >= 0) Wf *= eTot[sdi2 * NC + jf];
      wbd[d - 1] = (jb < NC) ? Wb : 0.f;
      if (jb < NC) Wb *= eTot[sdi2 * NC + jb];
    }
    size_t hbase_f = (size_t)(sdi2 * 2 + 0) * NC * 4096;
    size_t hbase_b = (size_t)(sdi2 * 2 + 1) * NC * 4096;
    int idx0 = tid * 16;
#pragma unroll
    for (int grp = 0; grp < 2; grp++) {
      int idx = idx0 + grp * 8;
      float af[8], ab[8];
#pragma unroll
      for (int e = 0; e < 8; e++) { af[e] = 0.f; ab[e] = 0.f; }
#pragma unroll
      for (int d = 1; d <= 7; d++) {
        int jf = chunk - d;
        if (jf >= 0) {
          short8 v = *(const short8*)(Hcb + hbase_f + (size_t)jf * 4096 + idx);
#pragma unroll
          for (int e = 0; e < 8; e++) af[e] += wfd[d - 1] * bf2f((u16)v[e]);
        }
        int jb = chunk + d;
        if (jb < NC) {
          short8 v = *(const short8*)(Hcb + hbase_b + (size_t)jb * 4096 + idx);
#pragma unroll
          for (int e = 0; e < 8; e++) ab[e] += wbd[d - 1] * bf2f((u16)v[e]);
        }
      }
      int p = idx >> 6, rn0 = idx & 63;
      short8 of, ob;
#pragma unroll
      for (int e = 0; e < 8; e++) {
        of[e] = (short)f2bf(af[e]);
        ob[e] = (short)f2bf(ab[e]);
      }
      *(short8*)(HTf + swz(p, rn0)) = of;
      *(short8*)(HTb + swz(p, rn0)) = ob;
    }
  }
  __syncthreads();

  f32x4 accF[4], accB[4];
#pragma unroll
  for (int j = 0; j < 4; j++)
#pragma unroll
    for (int r = 0; r < 4; r++) { accF[j][r] = 0.f; accB[j][r] = 0.f; }
  if (chunk > 0) {
    float rowScale = scf[w * 16 + lr];
#pragma unroll
    for (int kk = 0; kk < 2; kk++) {
      int k0 = kk * 32 + lq * 8;
      short8 afs = scale8(ldfrag(Cmat, w * 16 + lr, k0), rowScale);
#pragma unroll
      for (int j = 0; j < 4; j++)
        accF[j] = __builtin_amdgcn_mfma_f32_16x16x32_bf16(
            afs, ldfrag(HTf, j * 16 + lr, k0), accF[j], 0, 0, 0);
    }
  }
  if (chunk < NC - 1) {
    float rowScale = scb[w * 16 + lr];
#pragma unroll
    for (int kk = 0; kk < 2; kk++) {
      int k0 = kk * 32 + lq * 8;
      short8 afs = scale8(ldfrag(Cmat, w * 16 + lr, k0), rowScale);
#pragma unroll
      for (int j = 0; j < 4; j++)
        accB[j] = __builtin_amdgcn_mfma_f32_16x16x32_bf16(
            afs, ldfrag(HTb, j * 16 + lr, k0), accB[j], 0, 0, 0);
    }
  }
#pragma unroll
  for (int j = 0; j < 4; j++) {
    int p = j * 16 + lr;
#pragma unroll
    for (int r = 0; r < 4; r++) {
      size_t idx = (rowbase + w * 16 + lq * 4 + r) * DI + h * 64 + p;
      ysumb[idx] = f2bf(bf2f(ysumb[idx]) + accF[j][r] + accB[j][r]);
    }
  }
}

// =========================================================================
extern "C" void kernel_launch(void* const* d_in, const int* in_sizes, int n_in,
                              void* d_out, int out_size, void* d_ws, size_t ws_size,
                              hipStream_t stream) {
  const float* atom_tok = (const float*)d_in[0];
  const void*  mask_raw = d_in[1];
  const float* w_in   = (const float*)d_in[2];
  const float* conv_w = (const float*)d_in[3];
  const float* A_log  = (const float*)d_in[4];
  const float* dt_bias= (const float*)d_in[5];
  const float* Dp     = (const float*)d_in[6];
  const float* rms_w  = (const float*)d_in[7];
  const float* w_out  = (const float*)d_in[8];
  const float* pre_w  = (const float*)d_in[9];
  const float* ln_g   = (const float*)d_in[10];
  const float* ln_b   = (const float*)d_in[11];
  const float* w1     = (const float*)d_in[12];
  const float* b1     = (const float*)d_in[13];
  const float* w2     = (const float*)d_in[14];
  const float* b2     = (const float*)d_in[15];
  float* out = (float*)d_out;

  char* ws = (char*)d_ws;
  size_t off = 0;
  auto alloc = [&](size_t bytes) -> char* {
    char* p = ws + off;
    off += (bytes + 255) & ~(size_t)255;
    return p;
  };
  float* tok    = (float*)alloc((size_t)Mrows * Datom * 4);
  float* maskf  = (float*)alloc((size_t)Mrows * 4);
  u16*   xin    = (u16*)  alloc((size_t)Mrows * Datom * 2);
  u16*   projb  = (u16*)  alloc((size_t)Mrows * PSTR * 2);
  u16*   ysumb  = (u16*)  alloc((size_t)Mrows * DI * 2);
  u16*   Hcb    = (u16*)  alloc((size_t)Bsz * NH * 2 * NC * 4096 * 2);
  float* carrySc= (float*)alloc((size_t)Bsz * NH * NC * 128 * 4);
  float* eTot   = (float*)alloc((size_t)Bsz * NH * NC * 4);
  u16*   winT   = (u16*)  alloc((size_t)NL * PSTR * Datom * 2);
  u16*   woutT  = (u16*)  alloc((size_t)NL * Datom * DI * 2);
  u16*   w1T    = (u16*)  alloc((size_t)128 * Datom * 2);

  prologue<<<1440 + 32 + Mrows, 256, 0, stream>>>(
      mask_raw, maskf, w_in, w_out, w1, winT, woutT, w1T,
      atom_tok, pre_w, tok, xin);

  for (int l = 0; l < NL; l++) {
    const u16* winT_l = winT + (size_t)l * PSTR * Datom;
    gemm_in<<<dim3(Mrows / 128, 9), 256, 0, stream>>>(
        xin, winT_l, projb, PSTR, Datom);
    scan_fused<<<dim3(Bsz, NH, NC), 256, 0, stream>>>(
        projb, xin, winT_l, conv_w + l * 4 * DI, A_log + l * NH,
        dt_bias + l * NH, Dp + l * NH, maskf, ysumb, Hcb, carrySc, eTot);
    carry_add<<<dim3(Bsz, NH, NC), 256, 0, stream>>>(
        projb, Hcb, carrySc, eTot, ysumb);
    if (l < NL - 1)
      gemm_gate_out<1><<<Mrows / 32, 256, 0, stream>>>(
          ysumb, projb, rms_w + l * DI, woutT + (size_t)l * Datom * DI, tok,
          pre_w + (l + 1) * Datom, nullptr, tok, xin,
          nullptr, nullptr, nullptr, nullptr, nullptr, nullptr);
    else
      gemm_gate_out<2><<<Mrows / 32, 256, 0, stream>>>(
          ysumb, projb, rms_w + l * DI, woutT + (size_t)l * Datom * DI, tok,
          ln_g, ln_b, tok, nullptr,
          w1T, b1, w2, b2, maskf, out);
  }
}

// Round 17
// 308.802 us; speedup vs baseline: 1.0407x; 1.0407x over previous
//
#include <hip/hip_runtime.h>
#include <hip/hip_bf16.h>

#define DEV __device__ __forceinline__

static constexpr int Bsz   = 16;
static constexpr int Aseq  = 512;
static constexpr int Datom = 256;
static constexpr int NL    = 4;
static constexpr int DI    = 512;   // d_inner
static constexpr int NH    = 8;     // heads
static constexpr int DPROJ = 1160;
static constexpr int PSTR  = 1280;  // padded proj row stride
static constexpr int Mrows = Bsz * Aseq;  // 8192
static constexpr int NC    = 8;     // chunks
static constexpr int CB    = 64;    // chunk size

typedef __attribute__((ext_vector_type(8))) short short8;
typedef __attribute__((ext_vector_type(4))) float f32x4;
typedef unsigned int u32;
typedef unsigned short u16;

DEV u16 f2bf(float x) {
  __hip_bfloat16 h = __float2bfloat16(x);   // RNE, compiler pairs to cvt_pk
  u16 r; __builtin_memcpy(&r, &h, 2); return r;
}
DEV float bf2f(u16 b) {
  union { unsigned u; float f; } v; v.u = ((unsigned)b) << 16;
  return v.f;
}
DEV float fsilu(float x) {
  return x * __builtin_amdgcn_rcpf(1.f + __expf(-x));
}

DEV void gload16(const u16* g, u16* l) {
  __builtin_amdgcn_global_load_lds(
      (const __attribute__((address_space(1))) u32*)g,
      (__attribute__((address_space(3))) u32*)l, 16, 0, 0);
}

template<int NW>
DEV float block_sum(float v, float* sbuf) {
  int lane = threadIdx.x & 63, wid = threadIdx.x >> 6;
#pragma unroll
  for (int o = 32; o > 0; o >>= 1) v += __shfl_down(v, o);
  if (lane == 0) sbuf[wid] = v;
  __syncthreads();
  if (wid == 0) {
    float t = (lane < NW) ? sbuf[lane] : 0.f;
#pragma unroll
    for (int o = 4; o > 0; o >>= 1) t += __shfl_down(t, o);
    if (lane == 0) sbuf[0] = t;
  }
  __syncthreads();
  float r = sbuf[0];
  __syncthreads();
  return r;
}

// ===== PROLOGUE: weights transpose | mask build | rmsnorm+copy ==========
// flat grid: [0,1440) weights tiles, [1440,1472) mask, [1472,9664) rmsnorm.
__global__ __launch_bounds__(256)
void prologue(const void* mask_raw, float* maskf,
              const float* w_in, const float* w_out, const float* w1,
              u16* winT, u16* woutT, u16* w1T,
              const float* atok, const float* pre_w, float* tok, u16* xin) {
  __shared__ float T[64][65];
  __shared__ float sred[16];
  __shared__ int cnz, c3f;
  int bid = blockIdx.x, tid = threadIdx.x;

  if (bid < 1440) {
    int x = bid & 7, y = (bid >> 3) % 20, z = bid / 160;
    const float* src; u16* dst; int K, N, Npad;
    if (z < 4) {
      src = w_in + (size_t)z * Datom * DPROJ; dst = winT + (size_t)z * PSTR * Datom;
      K = Datom; N = DPROJ; Npad = PSTR;
    } else if (z < 8) {
      int l = z - 4;
      src = w_out + (size_t)l * DI * Datom; dst = woutT + (size_t)l * Datom * DI;
      K = DI; N = Datom; Npad = Datom;
    } else {
      src = w1; dst = w1T; K = Datom; N = 128; Npad = 128;
    }
    int k0 = x * 64, n0 = y * 64;
    if (k0 >= K || n0 >= Npad) return;
#pragma unroll
    for (int i = 0; i < 16; i++) {
      int lin = tid + i * 256;
      int kk = lin >> 6, nn = lin & 63;
      int n = n0 + nn;
      T[kk][nn] = (n < N) ? src[(size_t)(k0 + kk) * N + n] : 0.f;
    }
    __syncthreads();
#pragma unroll
    for (int i = 0; i < 16; i++) {
      int lin = tid + i * 256;
      int nn = lin >> 6, kk = lin & 63;
      dst[(size_t)(n0 + nn) * K + k0 + kk] = f2bf(T[kk][nn]);
    }
  } else if (bid < 1472) {
    if (tid == 0) { cnz = 0; c3f = 0; }
    __syncthreads();
    const unsigned char* mb = (const unsigned char*)mask_raw;
    int nz = 0, f3 = 0;
    for (int i = tid; i < 8192; i += 256) {
      unsigned char v = mb[i];
      nz += (v != 0);
      f3 += (v == 0x3f);
    }
    atomicAdd(&cnz, nz);
    atomicAdd(&c3f, f3);
    __syncthreads();
    int fl = (c3f > 500) ? 2 : ((cnz > 4500) ? 0 : 1);
    int i = (bid - 1440) * 256 + tid;
    float v;
    if (fl == 0)      v = ((const unsigned char*)mask_raw)[i] ? 1.f : 0.f;
    else if (fl == 1) v = ((const int*)mask_raw)[i] ? 1.f : 0.f;
    else              v = (((const float*)mask_raw)[i] != 0.f) ? 1.f : 0.f;
    maskf[i] = v;
  } else {
    int row = bid - 1472, c = tid;
    float v = atok[(size_t)row * Datom + c];
    tok[(size_t)row * Datom + c] = v;
    float tot = block_sum<4>(v * v, sred);
    float scale = rsqrtf(tot / (float)Datom + 1e-6f);
    xin[(size_t)row * Datom + c] = f2bf(v * scale * pre_w[c]);
  }
}

// ---------------- in-proj 128x128 bf16 MFMA GEMM -------------------------
__global__ __launch_bounds__(256)
void gemm_in(const u16* Abf, const u16* BTbf, u16* outp, float* side,
             int Ndim, int Kdim) {
  __shared__ __align__(16) u16 As[128 * 32];
  __shared__ __align__(16) u16 Bs[128 * 32];
  int tid = threadIdx.x, w = tid >> 6, lane = tid & 63;
  int wm = w >> 1, wn = w & 1;
  int r0 = blockIdx.x * 128, c0 = blockIdx.y * 128;
  int lq = lane >> 4, lr = lane & 15;
  const u16* Ag = Abf + (size_t)r0 * Kdim;
  const u16* Bg = BTbf + (size_t)c0 * Kdim;
  int srow[2], scol = (lane & 3) * 8;
  u16* ldst[2][2];
#pragma unroll
  for (int rr = 0; rr < 2; rr++) {
    int chunk = rr * 4 + w;
    srow[rr] = chunk * 16 + (lane >> 2);
    ldst[rr][0] = As + chunk * 512;
    ldst[rr][1] = Bs + chunk * 512;
  }
  f32x4 acc[4][4];
#pragma unroll
  for (int i = 0; i < 4; i++)
#pragma unroll
    for (int j = 0; j < 4; j++)
#pragma unroll
      for (int r = 0; r < 4; r++) acc[i][j][r] = 0.f;

  for (int k0 = 0; k0 < Kdim; k0 += 32) {
    __syncthreads();
#pragma unroll
    for (int rr = 0; rr < 2; rr++) {
      gload16(Ag + (size_t)srow[rr] * Kdim + k0 + scol, ldst[rr][0]);
      gload16(Bg + (size_t)srow[rr] * Kdim + k0 + scol, ldst[rr][1]);
    }
    __syncthreads();
    short8 af[4], bfr[4];
#pragma unroll
    for (int i = 0; i < 4; i++)
      af[i] = *(const short8*)(As + (wm * 64 + i * 16 + lr) * 32 + lq * 8);
#pragma unroll
    for (int j = 0; j < 4; j++)
      bfr[j] = *(const short8*)(Bs + (wn * 64 + j * 16 + lr) * 32 + lq * 8);
#pragma unroll
    for (int i = 0; i < 4; i++)
#pragma unroll
      for (int j = 0; j < 4; j++)
        acc[i][j] = __builtin_amdgcn_mfma_f32_16x16x32_bf16(af[i], bfr[j], acc[i][j], 0, 0, 0);
  }
#pragma unroll
  for (int i = 0; i < 4; i++)
#pragma unroll
    for (int j = 0; j < 4; j++)
#pragma unroll
      for (int r = 0; r < 4; r++) {
        int row = r0 + wm * 64 + i * 16 + lq * 4 + r;
        int col = c0 + wn * 64 + j * 16 + lr;
        size_t idx = (size_t)row * Ndim + col;
        float v = acc[i][j][r];
        outp[idx] = f2bf(v);
        if (col >= 1152 && col < 1160) side[row * 8 + col - 1152] = v;
      }
}

// ---- gate (y*silu(z), rms) + out-proj GEMM + residual + (rms | LN+head) --
template<int MODE>
__global__ __launch_bounds__(256)
void gemm_gate_out(const u16* ysumb, const u16* projb, const float* rw,
                   const u16* BTbf, const float* tok_in,
                   const float* aux1, const float* aux2,
                   float* tok_out, u16* dst16,
                   const u16* w1Tp, const float* b1p, const float* w2p,
                   const float* b2p, const float* maskfp, float* outf) {
  __shared__ __align__(16) u16 As[32 * 512];   // gated+normalized A (swizzled)
  __shared__ __align__(16) u16 Bs[256 * 32];
  __shared__ float part1[32][4];
  __shared__ float part2[32][4];
  int tid = threadIdx.x, w = tid >> 6, lane = tid & 63;
  int lq = lane >> 4, lr = lane & 15;
  int r0 = blockIdx.x * 32;

  // Phase A: gate + rms, values kept in registers, single LDS write.
  {
    int arow = tid >> 3, sub = tid & 7;
    size_t yb = (size_t)(r0 + arow) * DI;
    size_t pb = (size_t)(r0 + arow) * PSTR;
    short8 g8s[8];
    float sumsq = 0.f;
#pragma unroll
    for (int o = 0; o < 8; o++) {
      int col = sub * 64 + o * 8;
      short8 yv = *(const short8*)(ysumb + yb + col);
      short8 zv = *(const short8*)(projb + pb + col);
#pragma unroll
      for (int e = 0; e < 8; e++) {
        float y = bf2f((u16)yv[e]);
        float z = bf2f((u16)zv[e]);
        float g = y * z * __builtin_amdgcn_rcpf(1.f + __expf(-z));
        sumsq += g * g;
        g8s[o][e] = (short)f2bf(g);
      }
    }
#pragma unroll
    for (int m = 1; m < 8; m <<= 1) sumsq += __shfl_xor(sumsq, m);
    float scl = rsqrtf(sumsq / (float)DI + 1e-6f);
#pragma unroll
    for (int o = 0; o < 8; o++) {
      int col = sub * 64 + o * 8;
      int oct = (sub * 8 + o) ^ (arow & 7);
      short8 g8 = g8s[o];
      f32x4 w0 = *(const f32x4*)(rw + col);
      f32x4 w1 = *(const f32x4*)(rw + col + 4);
#pragma unroll
      for (int e = 0; e < 4; e++) {
        g8[e]     = (short)f2bf(bf2f((u16)g8[e]) * scl * w0[e]);
        g8[4 + e] = (short)f2bf(bf2f((u16)g8[4 + e]) * scl * w1[e]);
      }
      *(short8*)(As + arow * 512 + oct * 8) = g8;
    }
  }

  // Phase B: K-loop, A from LDS (persistent), B staged per iter.
  f32x4 acc[2][4];
#pragma unroll
  for (int i = 0; i < 2; i++)
#pragma unroll
    for (int j = 0; j < 4; j++)
#pragma unroll
      for (int r = 0; r < 4; r++) acc[i][j][r] = 0.f;

  for (int k0 = 0; k0 < 512; k0 += 32) {
    __syncthreads();
#pragma unroll
    for (int rr = 0; rr < 4; rr++) {
      int l = tid + rr * 256;
      int row = l >> 2, cc = l & 3;
      gload16(BTbf + (size_t)row * 512 + k0 + cc * 8, Bs + l * 8);
    }
    __syncthreads();
    int kq = k0 >> 3;
    short8 af[2], bfr[4];
#pragma unroll
    for (int i = 0; i < 2; i++) {
      int row = i * 16 + lr;
      af[i] = *(const short8*)(As + row * 512 + (((kq + lq) ^ (row & 7)) * 8));
    }
#pragma unroll
    for (int j = 0; j < 4; j++)
      bfr[j] = *(const short8*)(Bs + (w * 64 + j * 16 + lr) * 32 + lq * 8);
#pragma unroll
    for (int i = 0; i < 2; i++)
#pragma unroll
      for (int j = 0; j < 4; j++)
        acc[i][j] = __builtin_amdgcn_mfma_f32_16x16x32_bf16(af[i], bfr[j], acc[i][j], 0, 0, 0);
  }

  // Epilogue: residual + rowwise reduce + (rms | LN)
#pragma unroll
  for (int i = 0; i < 2; i++)
#pragma unroll
    for (int r = 0; r < 4; r++) {
      int lrow = i * 16 + lq * 4 + r;
      int row = r0 + lrow;
      float s1 = 0.f, s2 = 0.f;
#pragma unroll
      for (int j = 0; j < 4; j++) {
        int col = w * 64 + j * 16 + lr;
        float v = acc[i][j][r] + tok_in[(size_t)row * Datom + col];
        acc[i][j][r] = v;
        tok_out[(size_t)row * Datom + col] = v;
        s1 += v;
        s2 += v * v;
      }
#pragma unroll
      for (int m = 1; m < 16; m <<= 1) {
        s1 += __shfl_xor(s1, m);
        s2 += __shfl_xor(s2, m);
      }
      if (lr == 0) {
        part1[lrow][w] = s1;
        part2[lrow][w] = s2;
      }
    }
  __syncthreads();
#pragma unroll
  for (int i = 0; i < 2; i++)
#pragma unroll
    for (int r = 0; r < 4; r++) {
      int lrow = i * 16 + lq * 4 + r;
      int row = r0 + lrow;
      float t2 = part2[lrow][0] + part2[lrow][1] + part2[lrow][2] + part2[lrow][3];
      if constexpr (MODE == 1) {
        float scale = rsqrtf(t2 / (float)Datom + 1e-6f);
#pragma unroll
        for (int j = 0; j < 4; j++) {
          int col = w * 64 + j * 16 + lr;
          dst16[(size_t)row * Datom + col] = f2bf(acc[i][j][r] * scale * aux1[col]);
        }
      } else {
        float t1 = part1[lrow][0] + part1[lrow][1] + part1[lrow][2] + part1[lrow][3];
        float mu = t1 / (float)Datom;
        float var = t2 / (float)Datom - mu * mu;
        float rs = rsqrtf(var + 1e-5f);
#pragma unroll
        for (int j = 0; j < 4; j++) {
          int col = w * 64 + j * 16 + lr;
          float lnv = (acc[i][j][r] - mu) * rs * aux1[col] + aux2[col];
          int chunk = col >> 5;
          int cc = col & 31;
          As[chunk * 1024 + lrow * 32 + cc] = f2bf(lnv);
        }
      }
    }

  if constexpr (MODE == 2) {
    // ---- head: h1 = lnb32x256 @ w1T; gelu; dot w2 + b2; *mask -> outf ----
    __shared__ float hpart[32][2][3];
    __shared__ float sw2[387];
    for (int g = tid; g < 387; g += 256)
      sw2[g] = (g < 384) ? w2p[g] : b2p[g - 384];
    int wm2 = w >> 1, wn2 = w & 1;
    f32x4 hacc[4];
#pragma unroll
    for (int j = 0; j < 4; j++)
#pragma unroll
      for (int r = 0; r < 4; r++) hacc[j][r] = 0.f;

    for (int k0 = 0; k0 < 256; k0 += 32) {
      __syncthreads();
      {
        int l = tid, row = l >> 2, cc2 = l & 3;
        gload16(w1Tp + (size_t)row * 256 + k0 + cc2 * 8, Bs + l * 8);
        l = tid + 256; row = l >> 2; cc2 = l & 3;
        gload16(w1Tp + (size_t)row * 256 + k0 + cc2 * 8, Bs + l * 8);
      }
      __syncthreads();
      short8 af = *(const short8*)(As + (k0 >> 5) * 1024 + (wm2 * 16 + lr) * 32 + lq * 8);
#pragma unroll
      for (int j = 0; j < 4; j++) {
        short8 bfr = *(const short8*)(Bs + (wn2 * 64 + j * 16 + lr) * 32 + lq * 8);
        hacc[j] = __builtin_amdgcn_mfma_f32_16x16x32_bf16(af, bfr, hacc[j], 0, 0, 0);
      }
    }
#pragma unroll
    for (int r = 0; r < 4; r++) {
      int lrow2 = wm2 * 16 + lq * 4 + r;
      float p0 = 0.f, p1 = 0.f, p2 = 0.f;
#pragma unroll
      for (int j = 0; j < 4; j++) {
        int col = wn2 * 64 + j * 16 + lr;
        float v = hacc[j][r] + b1p[col];
        float ge = 0.5f * v * (1.f + erff(v * 0.70710678118654752f));
        p0 += ge * sw2[col * 3 + 0];
        p1 += ge * sw2[col * 3 + 1];
        p2 += ge * sw2[col * 3 + 2];
      }
#pragma unroll
      for (int m = 1; m < 16; m <<= 1) {
        p0 += __shfl_xor(p0, m);
        p1 += __shfl_xor(p1, m);
        p2 += __shfl_xor(p2, m);
      }
      if (lr == 0) {
        hpart[lrow2][wn2][0] = p0;
        hpart[lrow2][wn2][1] = p1;
        hpart[lrow2][wn2][2] = p2;
      }
    }
    __syncthreads();
    if (tid < 32) {
      int row = r0 + tid;
      float mk = maskfp[row];
#pragma unroll
      for (int k = 0; k < 3; k++)
        outf[(size_t)row * 3 + k] =
            (hpart[tid][0][k] + hpart[tid][1][k] + sw2[384 + k]) * mk;
    }
  }
}

// ---------------- chunked SSD scan helpers -------------------------------
DEV int swz(int r, int c)  { return (r << 6) | (c ^ ((r & 7) << 3)); }  // bf16 [64][64]

DEV short8 ldfrag(const u16* M, int row, int k0) {
  return *(const short8*)(M + swz(row, k0));
}
DEV short8 scale8(short8 a, float s) {
  short8 r;
#pragma unroll
  for (int i = 0; i < 8; i++) r[i] = (short)f2bf(bf2f((u16)a[i]) * s);
  return r;
}
DEV short8 scale8v(short8 a, const float* s) {
  short8 r;
#pragma unroll
  for (int i = 0; i < 8; i++) r[i] = (short)f2bf(bf2f((u16)a[i]) * s[i]);
  return r;
}

// Pass 1: conv+dt+local scan fused. S_sum = S_fwd + S_bwd -> ONE Y pass,
// combined H_fwd/H_bwd pass. 4 barriers.
__global__ __launch_bounds__(256, 4)
void scan_fused(const u16* projb, const float* dtb, const float* cw,
                const float* A_log, const float* dt_bias, const float* Dpv,
                const float* maskf, u16* ysumb, u16* Hcb, float* carrySc,
                float* eTot) {
  int b = blockIdx.x, h = blockIdx.y, chunk = blockIdx.z;
  int tid = threadIdx.x, w = tid >> 6, lane = tid & 63;
  int lq = lane >> 4, lr = lane & 15;
  __shared__ __align__(16) u16 Cmat[4096];  // C [t][n]; then S_sum
  __shared__ __align__(16) u16 Bmat[4096];  // B [s][n]
  __shared__ __align__(16) u16 XTm[4096];   // [p][s] swizzled
  __shared__ __align__(16) union { u16 BTm[4096]; u16 XCs[4416]; } U;
  __shared__ float cws[4][64];
  __shared__ float Pp[64], Qq[64], scf[64], scb[64], dts[64], ms[64], dpo[64];
  int base_t = chunk * CB;
  int sdi2 = b * NH + h;
  size_t rowbase = (size_t)b * Aseq + base_t;

  // [A] per-t scalars + decay prefix (wave 0); other waves stage
  if (w == 0) {
    float mk = maskf[rowbase + lane];
    float dtr = dtb[(rowbase + lane) * 8 + h] + dt_bias[h];
    float dtv = (dtr > 20.f) ? dtr : log1pf(expf(dtr));
    dtv *= mk;
    float lv = -expf(A_log[h]) * dtv;
    dts[lane] = dtv;
    ms[lane] = mk;
    dpo[lane] = Dpv[h] / fmaxf(dtv, 1e-30f);
    float v = lv;
#pragma unroll
    for (int o = 1; o < 64; o <<= 1) {
      float u = __shfl_up(v, o);
      if (lane >= o) v += u;
    }
    float Ltot = __shfl(v, 63);
    Pp[lane] = v;
    Qq[lane] = v - lv;
    scf[lane] = __expf(Ltot - v);
    scb[lane] = __expf(v - lv);
    size_t cs = ((size_t)sdi2 * NC + chunk) * 128;
    carrySc[cs + lane] = __expf(v);
    carrySc[cs + 64 + lane] = __expf(Ltot - (v - lv));
    if (lane == 0) eTot[sdi2 * NC + chunk] = __expf(Ltot);
  }
  // [B] stage B,C + conv window XCs (stride-69, conflict-free)
  for (int g = tid; g < 1024; g += 256) {
    int t = g >> 4, cc0 = (g & 15) * 8;
    short8 v = *(const short8*)(projb + (rowbase + t) * PSTR + 1024 + cc0);
    if (cc0 < 64) *(short8*)(Bmat + swz(t, cc0)) = v;
    else          *(short8*)(Cmat + swz(t, cc0 - 64)) = v;
  }
  for (int g = tid; g < 536; g += 256) {
    int ti = g >> 3, p0 = (g & 7) * 8;
    if (ti < 67) {
      int tg = base_t - 3 + ti;
      short8 v;
      if (tg >= 0) {
        v = *(const short8*)(projb + ((size_t)b * Aseq + tg) * PSTR + DI + h * 64 + p0);
      } else {
#pragma unroll
        for (int e = 0; e < 8; e++) v[e] = 0;
      }
#pragma unroll
      for (int e = 0; e < 8; e++) U.XCs[(p0 + e) * 69 + ti] = (u16)v[e];
    }
  }
  cws[tid >> 6][tid & 63] = cw[(tid >> 6) * DI + h * 64 + (tid & 63)];
  __syncthreads();  // (1)

  // [C] conv + silu + xdt into XTm (conflict-free)
  for (int g = tid; g < 4096; g += 256) {
    int p = g >> 6, t = g & 63;
    float acc = 0.f;
#pragma unroll
    for (int k = 0; k < 4; k++)
      acc += cws[k][p] * bf2f(U.XCs[p * 69 + t + k]);
    float xcv = fsilu(acc) * ms[t];
    XTm[swz(p, t)] = f2bf(xcv * dts[t]);
  }
  __syncthreads();  // (2) XCs dead; BTm may overwrite

  // [C2] BTm[rn][t] from Bmat (LDS->LDS) ; [D] G = C @ B^T
  for (int g = tid; g < 512; g += 256) {
    int t = g & 63, n0 = (g >> 6) * 8;
    short8 v = *(const short8*)(Bmat + swz(t, n0));
#pragma unroll
    for (int e = 0; e < 8; e++) U.BTm[swz(n0 + e, t)] = (u16)v[e];
  }
  f32x4 accG[4];
#pragma unroll
  for (int j = 0; j < 4; j++)
#pragma unroll
    for (int r = 0; r < 4; r++) accG[j][r] = 0.f;
#pragma unroll
  for (int kk = 0; kk < 2; kk++) {
    int k0 = kk * 32 + lq * 8;
    short8 afr = ldfrag(Cmat, w * 16 + lr, k0);
#pragma unroll
    for (int j = 0; j < 4; j++)
      accG[j] = __builtin_amdgcn_mfma_f32_16x16x32_bf16(
          afr, ldfrag(Bmat, j * 16 + lr, k0), accG[j], 0, 0, 0);
  }
  __syncthreads();  // (3)

  int trow[4];
#pragma unroll
  for (int r = 0; r < 4; r++) trow[r] = w * 16 + lq * 4 + r;

  // ---- S_sum = S_fwd + S_bwd -> Cmat (diag: 2*G + D/dt) ----
#pragma unroll
  for (int j = 0; j < 4; j++) {
    int s = j * 16 + lr;
    float Ls = Pp[s], Qs = Qq[s];
#pragma unroll
    for (int r = 0; r < 4; r++) {
      int t = trow[r];
      float g = 0.f;
      if (s <= t) g += accG[j][r] * __expf(Pp[t] - Ls);
      if (s >= t) g += accG[j][r] * __expf(Qs - Qq[t]);
      if (s == t) g += dpo[s];
      Cmat[swz(t, s)] = f2bf(g);
    }
  }
  __syncthreads();  // (4)

  // ---- combined Y + H_fwd + H_bwd ----
  f32x4 accY[4], accHf[4], accHb[4];
#pragma unroll
  for (int j = 0; j < 4; j++)
#pragma unroll
    for (int r = 0; r < 4; r++) { accY[j][r] = 0.f; accHf[j][r] = 0.f; accHb[j][r] = 0.f; }
#pragma unroll
  for (int kk = 0; kk < 2; kk++) {
    int k0 = kk * 32 + lq * 8;
    short8 aS  = ldfrag(Cmat, w * 16 + lr, k0);
    short8 aX  = ldfrag(XTm,  w * 16 + lr, k0);
    short8 aXf = scale8v(aX, &scf[k0]);
    short8 aXb = scale8v(aX, &scb[k0]);
#pragma unroll
    for (int j = 0; j < 4; j++)
      accY[j] = __builtin_amdgcn_mfma_f32_16x16x32_bf16(
          aS, ldfrag(XTm, j * 16 + lr, k0), accY[j], 0, 0, 0);
#pragma unroll
    for (int j = 0; j < 4; j++) {
      short8 bB = ldfrag(U.BTm, j * 16 + lr, k0);
      accHf[j] = __builtin_amdgcn_mfma_f32_16x16x32_bf16(aXf, bB, accHf[j], 0, 0, 0);
      accHb[j] = __builtin_amdgcn_mfma_f32_16x16x32_bf16(aXb, bB, accHb[j], 0, 0, 0);
    }
  }
  size_t hbf = ((size_t)(sdi2 * 2 + 0) * NC + chunk) * 4096;
  size_t hbb = ((size_t)(sdi2 * 2 + 1) * NC + chunk) * 4096;
#pragma unroll
  for (int j = 0; j < 4; j++) {
    int rn = j * 16 + lr;
#pragma unroll
    for (int r = 0; r < 4; r++) {
      int p = w * 16 + lq * 4 + r;
      Hcb[hbf + p * 64 + rn] = f2bf(accHf[j][r]);
      Hcb[hbb + p * 64 + rn] = f2bf(accHb[j][r]);
    }
  }
  // ---- y = (S_f + S_b) @ X ----
#pragma unroll
  for (int j = 0; j < 4; j++) {
    int p = j * 16 + lr;
#pragma unroll
    for (int r = 0; r < 4; r++)
      ysumb[(rowbase + trow[r]) * DI + h * 64 + p] = f2bf(accY[j][r]);
  }
}

// Pass 2: ysumb += carries IN PLACE; H_init = weighted sums of chunk states.
__global__ __launch_bounds__(256, 4)
void carry_add(const u16* projb, const u16* Hcb, const float* carrySc,
               const float* eTot, u16* ysumb) {
  int b = blockIdx.x, h = blockIdx.y, chunk = blockIdx.z;
  int tid = threadIdx.x, w = tid >> 6, lane = tid & 63;
  int lq = lane >> 4, lr = lane & 15;
  __shared__ __align__(16) u16 Cmat[4096];
  __shared__ __align__(16) u16 HTf[4096], HTb[4096];
  __shared__ float scf[64], scb[64];
  int base_t = chunk * CB;
  int sdi2 = b * NH + h;
  size_t rowbase = (size_t)b * Aseq + base_t;

  if (tid < 128) {
    size_t cs = ((size_t)sdi2 * NC + chunk) * 128;
    float v = carrySc[cs + tid];
    if (tid < 64) scf[tid] = v; else scb[tid - 64] = v;
  }
  for (int g = tid; g < 512; g += 256) {
    int t = g >> 3, n0 = (g & 7) * 8;
    *(short8*)(Cmat + swz(t, n0)) =
        *(const short8*)(projb + (rowbase + t) * PSTR + 1088 + n0);
  }
  {
    float wfd[7], wbd[7];
    float Wf = 1.f, Wb = 1.f;
#pragma unroll
    for (int d = 1; d <= 7; d++) {
      int jf = chunk - d, jb = chunk + d;
      wfd[d - 1] = (jf >= 0) ? Wf : 0.f;
      if (jf >= 0) Wf *= eTot[sdi2 * NC + jf];
      wbd[d - 1] = (jb < NC) ? Wb : 0.f;
      if (jb < NC) Wb *= eTot[sdi2 * NC + jb];
    }
    size_t hbase_f = (size_t)(sdi2 * 2 + 0) * NC * 4096;
    size_t hbase_b = (size_t)(sdi2 * 2 + 1) * NC * 4096;
    int idx0 = tid * 16;
#pragma unroll
    for (int grp = 0; grp < 2; grp++) {
      int idx = idx0 + grp * 8;
      float af[8], ab[8];
#pragma unroll
      for (int e = 0; e < 8; e++) { af[e] = 0.f; ab[e] = 0.f; }
#pragma unroll
      for (int d = 1; d <= 7; d++) {
        int jf = chunk - d;
        if (jf >= 0) {
          short8 v = *(const short8*)(Hcb + hbase_f + (size_t)jf * 4096 + idx);
#pragma unroll
          for (int e = 0; e < 8; e++) af[e] += wfd[d - 1] * bf2f((u16)v[e]);
        }
        int jb = chunk + d;
        if (jb < NC) {
          short8 v = *(const short8*)(Hcb + hbase_b + (size_t)jb * 4096 + idx);
#pragma unroll
          for (int e = 0; e < 8; e++) ab[e] += wbd[d - 1] * bf2f((u16)v[e]);
        }
      }
      int p = idx >> 6, rn0 = idx & 63;
      short8 of, ob;
#pragma unroll
      for (int e = 0; e < 8; e++) {
        of[e] = (short)f2bf(af[e]);
        ob[e] = (short)f2bf(ab[e]);
      }
      *(short8*)(HTf + swz(p, rn0)) = of;
      *(short8*)(HTb + swz(p, rn0)) = ob;
    }
  }
  __syncthreads();

  f32x4 accF[4], accB[4];
#pragma unroll
  for (int j = 0; j < 4; j++)
#pragma unroll
    for (int r = 0; r < 4; r++) { accF[j][r] = 0.f; accB[j][r] = 0.f; }
  if (chunk > 0) {
    float rowScale = scf[w * 16 + lr];
#pragma unroll
    for (int kk = 0; kk < 2; kk++) {
      int k0 = kk * 32 + lq * 8;
      short8 afs = scale8(ldfrag(Cmat, w * 16 + lr, k0), rowScale);
#pragma unroll
      for (int j = 0; j < 4; j++)
        accF[j] = __builtin_amdgcn_mfma_f32_16x16x32_bf16(
            afs, ldfrag(HTf, j * 16 + lr, k0), accF[j], 0, 0, 0);
    }
  }
  if (chunk < NC - 1) {
    float rowScale = scb[w * 16 + lr];
#pragma unroll
    for (int kk = 0; kk < 2; kk++) {
      int k0 = kk * 32 + lq * 8;
      short8 afs = scale8(ldfrag(Cmat, w * 16 + lr, k0), rowScale);
#pragma unroll
      for (int j = 0; j < 4; j++)
        accB[j] = __builtin_amdgcn_mfma_f32_16x16x32_bf16(
            afs, ldfrag(HTb, j * 16 + lr, k0), accB[j], 0, 0, 0);
    }
  }
#pragma unroll
  for (int j = 0; j < 4; j++) {
    int p = j * 16 + lr;
#pragma unroll
    for (int r = 0; r < 4; r++) {
      size_t idx = (rowbase + w * 16 + lq * 4 + r) * DI + h * 64 + p;
      ysumb[idx] = f2bf(bf2f(ysumb[idx]) + accF[j][r] + accB[j][r]);
    }
  }
}

// =========================================================================
extern "C" void kernel_launch(void* const* d_in, const int* in_sizes, int n_in,
                              void* d_out, int out_size, void* d_ws, size_t ws_size,
                              hipStream_t stream) {
  const float* atom_tok = (const float*)d_in[0];
  const void*  mask_raw = d_in[1];
  const float* w_in   = (const float*)d_in[2];
  const float* conv_w = (const float*)d_in[3];
  const float* A_log  = (const float*)d_in[4];
  const float* dt_bias= (const float*)d_in[5];
  const float* Dp     = (const float*)d_in[6];
  const float* rms_w  = (const float*)d_in[7];
  const float* w_out  = (const float*)d_in[8];
  const float* pre_w  = (const float*)d_in[9];
  const float* ln_g   = (const float*)d_in[10];
  const float* ln_b   = (const float*)d_in[11];
  const float* w1     = (const float*)d_in[12];
  const float* b1     = (const float*)d_in[13];
  const float* w2     = (const float*)d_in[14];
  const float* b2     = (const float*)d_in[15];
  float* out = (float*)d_out;

  char* ws = (char*)d_ws;
  size_t off = 0;
  auto alloc = [&](size_t bytes) -> char* {
    char* p = ws + off;
    off += (bytes + 255) & ~(size_t)255;
    return p;
  };
  float* tok    = (float*)alloc((size_t)Mrows * Datom * 4);
  float* maskf  = (float*)alloc((size_t)Mrows * 4);
  u16*   xin    = (u16*)  alloc((size_t)Mrows * Datom * 2);
  u16*   projb  = (u16*)  alloc((size_t)Mrows * PSTR * 2);
  float* dtb    = (float*)alloc((size_t)Mrows * 8 * 4);
  u16*   ysumb  = (u16*)  alloc((size_t)Mrows * DI * 2);
  u16*   Hcb    = (u16*)  alloc((size_t)Bsz * NH * 2 * NC * 4096 * 2);
  float* carrySc= (float*)alloc((size_t)Bsz * NH * NC * 128 * 4);
  float* eTot   = (float*)alloc((size_t)Bsz * NH * NC * 4);
  u16*   winT   = (u16*)  alloc((size_t)NL * PSTR * Datom * 2);
  u16*   woutT  = (u16*)  alloc((size_t)NL * Datom * DI * 2);
  u16*   w1T    = (u16*)  alloc((size_t)128 * Datom * 2);

  prologue<<<1440 + 32 + Mrows, 256, 0, stream>>>(
      mask_raw, maskf, w_in, w_out, w1, winT, woutT, w1T,
      atom_tok, pre_w, tok, xin);

  for (int l = 0; l < NL; l++) {
    gemm_in<<<dim3(Mrows / 128, PSTR / 128), 256, 0, stream>>>(
        xin, winT + (size_t)l * PSTR * Datom, projb, dtb, PSTR, Datom);
    scan_fused<<<dim3(Bsz, NH, NC), 256, 0, stream>>>(
        projb, dtb, conv_w + l * 4 * DI, A_log + l * NH, dt_bias + l * NH,
        Dp + l * NH, maskf, ysumb, Hcb, carrySc, eTot);
    carry_add<<<dim3(Bsz, NH, NC), 256, 0, stream>>>(
        projb, Hcb, carrySc, eTot, ysumb);
    if (l < NL - 1)
      gemm_gate_out<1><<<Mrows / 32, 256, 0, stream>>>(
          ysumb, projb, rms_w + l * DI, woutT + (size_t)l * Datom * DI, tok,
          pre_w + (l + 1) * Datom, nullptr, tok, xin,
          nullptr, nullptr, nullptr, nullptr, nullptr, nullptr);
    else
      gemm_gate_out<2><<<Mrows / 32, 256, 0, stream>>>(
          ysumb, projb, rms_w + l * DI, woutT + (size_t)l * Datom * DI, tok,
          ln_g, ln_b, tok, nullptr,
          w1T, b1, w2, b2, maskf, out);
  }
}